// Round 12
// baseline (872.073 us; speedup 1.0000x reference)
//
#include <hip/hip_runtime.h>
#include <hip/hip_bf16.h>

#define HID 64
#define MAXNB 2048   // max buckets (N <= 131072)
#define NBLK 128     // radix partition blocks
#define FILL_T 1024  // threads for hist/fill
#define SENT 0xFFFFFFFFu

__device__ __forceinline__ float bf2f(unsigned short u) {
    return __uint_as_float(((unsigned)u) << 16);
}
__device__ __forceinline__ unsigned short f2bf(float f) {
    __hip_bfloat16 b = __float2bfloat16(f);  // RNE
    return *(unsigned short*)&b;
}
__device__ __host__ __forceinline__ int ceil16(int c) { return (c + 15) & ~15; }

// ================= radix partition by bucket (bucket = dst >> 6) =================

__global__ __launch_bounds__(FILL_T) void radix_hist_kernel(
    const int* __restrict__ ei, int* __restrict__ H, int* __restrict__ bhist,
    int* __restrict__ bhist_pad, int E, int NB, int C) {
    __shared__ int lh[MAXNB];
    int blk = blockIdx.x, tid = threadIdx.x;
    for (int i = tid; i < NB; i += FILL_T) lh[i] = 0;
    __syncthreads();
    int lo = blk * C, hi = min(lo + C, E);
    for (int e = lo + tid; e < hi; e += FILL_T) atomicAdd(&lh[ei[E + e] >> 6], 1);
    __syncthreads();
    for (int i = tid; i < NB; i += FILL_T) {
        int v = lh[i];
        H[blk * NB + i] = v;
        if (v) {
            atomicAdd(&bhist[i], v);
            atomicAdd(&bhist_pad[i], ceil16(v));
        }
    }
}

__global__ __launch_bounds__(256) void scan_kernel(
    const int* __restrict__ bhist, const int* __restrict__ bhist_pad,
    int* __restrict__ pptr, int* __restrict__ cptr, int* __restrict__ gcur, int NB) {
    __shared__ int ssum[256];
    __shared__ int psum[256];
    int tid = threadIdx.x;
    int C = (NB + 255) / 256;
    int lo = tid * C, hi = min(lo + C, NB);
    int s = 0, p = 0;
    for (int i = lo; i < hi; i++) { s += bhist[i]; p += bhist_pad[i]; }
    ssum[tid] = s; psum[tid] = p;
    __syncthreads();
    for (int off = 1; off < 256; off <<= 1) {
        int v = (tid >= off) ? ssum[tid - off] : 0;
        int w = (tid >= off) ? psum[tid - off] : 0;
        __syncthreads();
        ssum[tid] += v; psum[tid] += w;
        __syncthreads();
    }
    int runc = (tid == 0) ? 0 : ssum[tid - 1];
    int runp = (tid == 0) ? 0 : psum[tid - 1];
    for (int i = lo; i < hi; i++) {
        cptr[i] = runc;
        pptr[i] = runp;
        gcur[i] = runp;
        runc += bhist[i];
        runp += bhist_pad[i];
    }
    if (hi == NB) { cptr[NB] = runc; pptr[NB] = runp; }
}

__global__ __launch_bounds__(FILL_T) void radix_fill_kernel(
    const int* __restrict__ ei, const int* __restrict__ H, int* __restrict__ gcur,
    unsigned* __restrict__ ebuf, int E, int NB, int C) {
    __shared__ int lcur[MAXNB];
    __shared__ int lend[MAXNB];
    int blk = blockIdx.x, tid = threadIdx.x;
    for (int i = tid; i < NB; i += FILL_T) {
        int cntb = H[blk * NB + i];
        int padc = ceil16(cntb);
        int start = padc ? atomicAdd(&gcur[i], padc) : 0;
        lcur[i] = start;
        lend[i] = start + padc;
    }
    __syncthreads();
    int lo = blk * C, hi = min(lo + C, E);
    for (int e = lo + tid; e < hi; e += FILL_T) {
        int s = ei[e];
        int d = ei[E + e];
        int pos = atomicAdd(&lcur[d >> 6], 1);
        ebuf[pos] = ((unsigned)s << 6) | (unsigned)(d & 63);
    }
    __syncthreads();
    for (int i = tid; i < NB; i += FILL_T) {
        for (int p = lcur[i]; p < lend[i]; p++) ebuf[p] = SENT;
    }
}

__global__ __launch_bounds__(256) void node_csr_kernel(
    const int* __restrict__ pptr, const int* __restrict__ cptr,
    const unsigned* __restrict__ ebuf,
    int* __restrict__ row_ptr, int* __restrict__ col, float* __restrict__ dinv,
    int N, int NB) {
    __shared__ int lcnt[64];
    __shared__ int loff[64];
    __shared__ int lcur[64];
    int bkt = blockIdx.x, tid = threadIdx.x;
    int beg = pptr[bkt], end = pptr[bkt + 1];
    int cbeg = cptr[bkt];
    if (tid < 64) lcnt[tid] = 0;
    __syncthreads();
    for (int e = beg + tid; e < end; e += 256) {
        unsigned ev = ebuf[e];
        if (ev != SENT) atomicAdd(&lcnt[ev & 63u], 1);
    }
    __syncthreads();
    if (tid == 0) {
        int run = cbeg;
        for (int i = 0; i < 64; i++) { loff[i] = run; lcur[i] = run; run += lcnt[i]; }
    }
    __syncthreads();
    if (tid < 64) {
        int node = (bkt << 6) + tid;
        if (node < N) {
            row_ptr[node] = loff[tid];
            dinv[node] = rsqrtf((float)(lcnt[tid] + 1));  // +1 self loop
        }
    }
    if (tid == 0 && bkt == NB - 1) row_ptr[N] = cptr[NB];
    for (int e = beg + tid; e < end; e += 256) {
        unsigned ev = ebuf[e];
        if (ev == SENT) continue;
        int pos = atomicAdd(&lcur[ev & 63u], 1);
        col[pos] = (int)(ev >> 6);
    }
}

// ================= g = bf16(dinv * (in @ W)) =================
template <typename Tin, int K>
__global__ void gemm_g_kernel(const Tin* __restrict__ in,
                              const float* __restrict__ W,
                              const float* __restrict__ dinv,
                              unsigned short* __restrict__ g, int N) {
    __shared__ float sW[K * HID];
    __shared__ float sIn[16 * K];
    int tid = threadIdx.x;
    for (int idx = tid; idx < K * HID; idx += 256) sW[idx] = W[idx];
    int base = blockIdx.x * 16;
    for (int idx = tid; idx < 16 * K; idx += 256) {
        int r = idx / K, c = idx % K;
        int node = base + r;
        float v = 0.f;
        if (node < N) {
            Tin t = in[(long long)node * K + c];
            if constexpr (sizeof(Tin) == 2) v = bf2f((unsigned short)t);
            else v = (float)t;
        }
        sIn[idx] = v;
    }
    __syncthreads();
    int j = tid & 63;
    int si = tid >> 6;
#pragma unroll
    for (int u = 0; u < 4; u++) {
        int r = si * 4 + u;
        int node = base + r;
        if (node >= N) continue;
        float acc = 0.f;
#pragma unroll
        for (int k = 0; k < K; k++) acc += sIn[r * K + k] * sW[k * HID + j];
        g[(long long)node * HID + j] = f2bf(dinv[node] * acc);
    }
}

// ================= gather + combine (paired-row dword loads, ILP-4) =================
// One wave per dst node. Lanes 0-31 process even edges, 32-63 odd edges; each lane
// loads one dword = 2 bf16 features, so one wave-load fetches TWO rows. Full 64-edge
// chunks run unpredicated with 4 independent loads in flight (8 edges/iteration).
__global__ __launch_bounds__(256) void gather_kernel(
    const int* __restrict__ row_ptr, const int* __restrict__ col,
    const unsigned* __restrict__ g32, const float* __restrict__ dinv,
    const float* __restrict__ bias, unsigned* __restrict__ h32, int N) {
    int node = blockIdx.x * 4 + (threadIdx.x >> 6);
    int lane = threadIdx.x & 63;
    if (node >= N) return;
    int half = lane >> 5;     // 0: even edges, 1: odd edges
    int fl = lane & 31;       // dword index within row (features 2fl, 2fl+1)
    int beg = row_ptr[node], end = row_ptr[node + 1];
    float s0 = 0.f, s1 = 0.f;
    int e0 = beg;
    // full chunks: 64 edges, no predication, ILP-4
    for (; e0 + 64 <= end; e0 += 64) {
        int cs = col[e0 + lane];
#pragma unroll
        for (int j = 0; j < 32; j += 4) {
            int a0 = __shfl(cs, 2 * j + half);
            int a1 = __shfl(cs, 2 * j + 2 + half);
            int a2 = __shfl(cs, 2 * j + 4 + half);
            int a3 = __shfl(cs, 2 * j + 6 + half);
            unsigned d0 = g32[(long long)a0 * 32 + fl];
            unsigned d1 = g32[(long long)a1 * 32 + fl];
            unsigned d2 = g32[(long long)a2 * 32 + fl];
            unsigned d3 = g32[(long long)a3 * 32 + fl];
            s0 += (__uint_as_float(d0 << 16) + __uint_as_float(d1 << 16)) +
                  (__uint_as_float(d2 << 16) + __uint_as_float(d3 << 16));
            s1 += (__uint_as_float(d0 & 0xffff0000u) + __uint_as_float(d1 & 0xffff0000u)) +
                  (__uint_as_float(d2 & 0xffff0000u) + __uint_as_float(d3 & 0xffff0000u));
        }
    }
    // tail chunk (< 64 edges), predicated
    if (e0 < end) {
        int myE = e0 + lane;
        int cs = (myE < end) ? col[myE] : 0;
        int cnt = end - e0;
        int pairs = (cnt + 1) >> 1;
        for (int j = 0; j < pairs; j++) {
            int idx = 2 * j + half;
            int s = __shfl(cs, idx);
            if (idx < cnt) {
                unsigned d = g32[(long long)s * 32 + fl];
                s0 += __uint_as_float(d << 16);
                s1 += __uint_as_float(d & 0xffff0000u);
            }
        }
    }
    // combine even/odd halves
    s0 += __shfl_xor(s0, 32);
    s1 += __shfl_xor(s1, 32);
    if (half == 0) {
        unsigned d = g32[(long long)node * 32 + fl];  // self loop
        s0 += __uint_as_float(d << 16);
        s1 += __uint_as_float(d & 0xffff0000u);
        float dv = dinv[node];
        float v0 = dv * s0 + bias[2 * fl];
        float v1 = dv * s1 + bias[2 * fl + 1];
        v0 = v0 > 0.f ? v0 : 0.f;
        v1 = v1 > 0.f ? v1 : 0.f;
        h32[(long long)node * 32 + fl] =
            (unsigned)f2bf(v0) | (((unsigned)f2bf(v1)) << 16);
    }
}

// ================= pooling: segmented reduction (batch is sorted) =================
__global__ void pool_kernel(const unsigned short* __restrict__ h, const int* __restrict__ batch,
                            float* __restrict__ sums, float* __restrict__ cnt, int N) {
    int wave = blockIdx.x * 4 + (threadIdx.x >> 6);
    int lane = threadIdx.x & 63;
    int lo = wave * 64;
    if (lo >= N) return;
    int hi = min(lo + 64, N);
    int curb = batch[lo];
    float sum = 0.f;
    int nseg = 0;
    for (int i = lo; i < hi; i++) {
        int b = batch[i];
        if (b != curb) {
            atomicAdd(&sums[curb * HID + lane], sum);
            if (lane == 0) atomicAdd(&cnt[curb], (float)nseg);
            curb = b; sum = 0.f; nseg = 0;
        }
        sum += bf2f(h[(long long)i * HID + lane]);
        nseg++;
    }
    atomicAdd(&sums[curb * HID + lane], sum);
    if (lane == 0) atomicAdd(&cnt[curb], (float)nseg);
}

// ================= final MLP head =================
__global__ void final_kernel(const float* __restrict__ sums, const float* __restrict__ cnt,
                             const float* __restrict__ Wf1, const float* __restrict__ bf1,
                             const float* __restrict__ Wf2, const float* __restrict__ bf2,
                             float* __restrict__ out) {
    __shared__ float sW1[HID * 32];
    __shared__ float sW2[32];
    int tid = threadIdx.x;
    for (int idx = tid; idx < HID * 32; idx += 128) sW1[idx] = Wf1[idx];
    if (tid < 32) sW2[tid] = Wf2[tid];
    __syncthreads();
    int b = tid;
    float pooled[HID];
    float c = fmaxf(cnt[b], 1.0f);
#pragma unroll
    for (int j = 0; j < HID; j++) pooled[j] = sums[b * HID + j] / c;
    float o = bf2[0];
#pragma unroll 4
    for (int hd = 0; hd < 32; hd++) {
        float z = bf1[hd];
#pragma unroll
        for (int j = 0; j < HID; j++) z += pooled[j] * sW1[j * 32 + hd];
        z = fmaxf(z, 0.f);
        o += z * sW2[hd];
    }
    out[b] = o;
}

extern "C" void kernel_launch(void* const* d_in, const int* in_sizes, int n_in,
                              void* d_out, int out_size, void* d_ws, size_t ws_size,
                              hipStream_t stream) {
    const float* x     = (const float*)d_in[0];
    const int*   ei    = (const int*)d_in[1];
    const int*   batch = (const int*)d_in[3];
    const float* W1  = (const float*)d_in[4];
    const float* b1  = (const float*)d_in[5];
    const float* W2  = (const float*)d_in[6];
    const float* b2  = (const float*)d_in[7];
    const float* W3  = (const float*)d_in[8];
    const float* b3  = (const float*)d_in[9];
    const float* Wf1 = (const float*)d_in[10];
    const float* bf1 = (const float*)d_in[11];
    const float* Wf2 = (const float*)d_in[12];
    const float* bf2 = (const float*)d_in[13];
    float* out = (float*)d_out;

    const int N  = in_sizes[0] / 16;   // 100000
    const int E  = in_sizes[1] / 2;    // 3200000
    const int NB = (N + 63) / 64;      // 1563 buckets
    const size_t EBUF_CAP = (size_t)E + (size_t)NBLK * NB * 15;

    // workspace layout (~62 MB)
    char* ws = (char*)d_ws;
    size_t o = 0;
    float*          dinv    = (float*)(ws + o);          o += ((size_t)N * 4 + 4095) / 4096 * 4096;
    int*            row_ptr = (int*)(ws + o);            o += ((size_t)(N + 1) * 4 + 4095) / 4096 * 4096;
    int*            pptr    = (int*)(ws + o);            o += ((size_t)(NB + 1) * 4 + 4095) / 4096 * 4096;
    int*            cptr    = (int*)(ws + o);            o += ((size_t)(NB + 1) * 4 + 4095) / 4096 * 4096;
    int*            bhist   = (int*)(ws + o);            o += ((size_t)(2 * NB) * 4 + 4095) / 4096 * 4096;
    int*            bhist_pad = bhist + NB;
    int*            gcur    = (int*)(ws + o);            o += ((size_t)NB * 4 + 4095) / 4096 * 4096;
    int*            H       = (int*)(ws + o);            o += ((size_t)NBLK * NB * 4 + 4095) / 4096 * 4096;
    unsigned*       ebuf    = (unsigned*)(ws + o);       o += EBUF_CAP * 4;
    int*            col     = (int*)(ws + o);            o += (size_t)E * 4;
    unsigned short* A       = (unsigned short*)(ws + o); o += (size_t)N * HID * 2;
    unsigned short* B       = (unsigned short*)(ws + o); o += (size_t)N * HID * 2;
    float*          sums    = (float*)(ws + o);          o += 128 * HID * 4;
    float*          cnt     = (float*)(ws + o);          o += 128 * 4;
    (void)ws_size;

    const int T = 256;
    const int Cchunk = (E + NBLK - 1) / NBLK;
    const int gGm = (N + 15) / 16;
    const int gGa = (N + 3) / 4;
    const int gPool = ((N + 63) / 64 + 3) / 4;

    // ---- CSR build: aligned radix partition, then per-bucket counting sort ----
    hipMemsetAsync(bhist, 0, (size_t)(2 * NB) * 4, stream);
    radix_hist_kernel<<<NBLK, FILL_T, 0, stream>>>(ei, H, bhist, bhist_pad, E, NB, Cchunk);
    scan_kernel<<<1, T, 0, stream>>>(bhist, bhist_pad, pptr, cptr, gcur, NB);
    radix_fill_kernel<<<NBLK, FILL_T, 0, stream>>>(ei, H, gcur, ebuf, E, NB, Cchunk);
    node_csr_kernel<<<NB, T, 0, stream>>>(pptr, cptr, ebuf, row_ptr, col, dinv, N, NB);

    // ---- layer 1: x(f32, K=16) -> A -> gather -> B ----
    gemm_g_kernel<float, 16><<<gGm, T, 0, stream>>>(x, W1, dinv, A, N);
    gather_kernel<<<gGa, T, 0, stream>>>(row_ptr, col, (const unsigned*)A, dinv, b1, (unsigned*)B, N);

    // ---- layer 2: B -> B (in-place gemm) -> gather -> A ----
    gemm_g_kernel<unsigned short, 64><<<gGm, T, 0, stream>>>(B, W2, dinv, B, N);
    gather_kernel<<<gGa, T, 0, stream>>>(row_ptr, col, (const unsigned*)B, dinv, b2, (unsigned*)A, N);

    // ---- layer 3: A -> A -> gather -> B ----
    gemm_g_kernel<unsigned short, 64><<<gGm, T, 0, stream>>>(A, W3, dinv, A, N);
    gather_kernel<<<gGa, T, 0, stream>>>(row_ptr, col, (const unsigned*)A, dinv, b3, (unsigned*)B, N);

    // ---- pool + head ----
    hipMemsetAsync(sums, 0, (128 * HID + 128) * 4, stream);
    pool_kernel<<<gPool, T, 0, stream>>>(B, batch, sums, cnt, N);
    final_kernel<<<1, 128, 0, stream>>>(sums, cnt, Wf1, bf1, Wf2, bf2, out);
}

// Round 13
// 580.363 us; speedup vs baseline: 1.5026x; 1.5026x over previous
//
#include <hip/hip_runtime.h>
#include <hip/hip_bf16.h>

#define HID 64
#define MAXNB 2048   // max buckets (N <= 131072)
#define NBLK 128     // radix partition blocks
#define FILL_T 1024  // threads for hist/fill
#define SENT 0xFFFFFFFFu

__device__ __forceinline__ float bf2f(unsigned short u) {
    return __uint_as_float(((unsigned)u) << 16);
}
__device__ __forceinline__ unsigned short f2bf(float f) {
    __hip_bfloat16 b = __float2bfloat16(f);  // RNE
    return *(unsigned short*)&b;
}
__device__ __host__ __forceinline__ int ceil16(int c) { return (c + 15) & ~15; }

// ================= radix partition by bucket (bucket = dst >> 6) =================

__global__ __launch_bounds__(FILL_T) void radix_hist_kernel(
    const int* __restrict__ ei, int* __restrict__ H, int* __restrict__ bhist,
    int* __restrict__ bhist_pad, int E, int NB, int C) {
    __shared__ int lh[MAXNB];
    int blk = blockIdx.x, tid = threadIdx.x;
    for (int i = tid; i < NB; i += FILL_T) lh[i] = 0;
    __syncthreads();
    int lo = blk * C, hi = min(lo + C, E);
    for (int e = lo + tid; e < hi; e += FILL_T) atomicAdd(&lh[ei[E + e] >> 6], 1);
    __syncthreads();
    for (int i = tid; i < NB; i += FILL_T) {
        int v = lh[i];
        H[blk * NB + i] = v;
        if (v) {
            atomicAdd(&bhist[i], v);
            atomicAdd(&bhist_pad[i], ceil16(v));
        }
    }
}

__global__ __launch_bounds__(256) void scan_kernel(
    const int* __restrict__ bhist, const int* __restrict__ bhist_pad,
    int* __restrict__ pptr, int* __restrict__ cptr, int* __restrict__ gcur, int NB) {
    __shared__ int ssum[256];
    __shared__ int psum[256];
    int tid = threadIdx.x;
    int C = (NB + 255) / 256;
    int lo = tid * C, hi = min(lo + C, NB);
    int s = 0, p = 0;
    for (int i = lo; i < hi; i++) { s += bhist[i]; p += bhist_pad[i]; }
    ssum[tid] = s; psum[tid] = p;
    __syncthreads();
    for (int off = 1; off < 256; off <<= 1) {
        int v = (tid >= off) ? ssum[tid - off] : 0;
        int w = (tid >= off) ? psum[tid - off] : 0;
        __syncthreads();
        ssum[tid] += v; psum[tid] += w;
        __syncthreads();
    }
    int runc = (tid == 0) ? 0 : ssum[tid - 1];
    int runp = (tid == 0) ? 0 : psum[tid - 1];
    for (int i = lo; i < hi; i++) {
        cptr[i] = runc;
        pptr[i] = runp;
        gcur[i] = runp;
        runc += bhist[i];
        runp += bhist_pad[i];
    }
    if (hi == NB) { cptr[NB] = runc; pptr[NB] = runp; }
}

__global__ __launch_bounds__(FILL_T) void radix_fill_kernel(
    const int* __restrict__ ei, const int* __restrict__ H, int* __restrict__ gcur,
    unsigned* __restrict__ ebuf, int E, int NB, int C) {
    __shared__ int lcur[MAXNB];
    __shared__ int lend[MAXNB];
    int blk = blockIdx.x, tid = threadIdx.x;
    for (int i = tid; i < NB; i += FILL_T) {
        int cntb = H[blk * NB + i];
        int padc = ceil16(cntb);
        int start = padc ? atomicAdd(&gcur[i], padc) : 0;
        lcur[i] = start;
        lend[i] = start + padc;
    }
    __syncthreads();
    int lo = blk * C, hi = min(lo + C, E);
    for (int e = lo + tid; e < hi; e += FILL_T) {
        int s = ei[e];
        int d = ei[E + e];
        int pos = atomicAdd(&lcur[d >> 6], 1);
        ebuf[pos] = ((unsigned)s << 6) | (unsigned)(d & 63);
    }
    __syncthreads();
    for (int i = tid; i < NB; i += FILL_T) {
        for (int p = lcur[i]; p < lend[i]; p++) ebuf[p] = SENT;
    }
}

__global__ __launch_bounds__(256) void node_csr_kernel(
    const int* __restrict__ pptr, const int* __restrict__ cptr,
    const unsigned* __restrict__ ebuf,
    int* __restrict__ row_ptr, int* __restrict__ col, float* __restrict__ dinv,
    int N, int NB) {
    __shared__ int lcnt[64];
    __shared__ int loff[64];
    __shared__ int lcur[64];
    int bkt = blockIdx.x, tid = threadIdx.x;
    int beg = pptr[bkt], end = pptr[bkt + 1];
    int cbeg = cptr[bkt];
    if (tid < 64) lcnt[tid] = 0;
    __syncthreads();
    for (int e = beg + tid; e < end; e += 256) {
        unsigned ev = ebuf[e];
        if (ev != SENT) atomicAdd(&lcnt[ev & 63u], 1);
    }
    __syncthreads();
    if (tid == 0) {
        int run = cbeg;
        for (int i = 0; i < 64; i++) { loff[i] = run; lcur[i] = run; run += lcnt[i]; }
    }
    __syncthreads();
    if (tid < 64) {
        int node = (bkt << 6) + tid;
        if (node < N) {
            row_ptr[node] = loff[tid];
            dinv[node] = rsqrtf((float)(lcnt[tid] + 1));  // +1 self loop
        }
    }
    if (tid == 0 && bkt == NB - 1) row_ptr[N] = cptr[NB];
    for (int e = beg + tid; e < end; e += 256) {
        unsigned ev = ebuf[e];
        if (ev == SENT) continue;
        int pos = atomicAdd(&lcur[ev & 63u], 1);
        col[pos] = (int)(ev >> 6);
    }
}

// ================= g = bf16(dinv * (in @ W)) =================
template <typename Tin, int K>
__global__ void gemm_g_kernel(const Tin* __restrict__ in,
                              const float* __restrict__ W,
                              const float* __restrict__ dinv,
                              unsigned short* __restrict__ g, int N) {
    __shared__ float sW[K * HID];
    __shared__ float sIn[16 * K];
    int tid = threadIdx.x;
    for (int idx = tid; idx < K * HID; idx += 256) sW[idx] = W[idx];
    int base = blockIdx.x * 16;
    for (int idx = tid; idx < 16 * K; idx += 256) {
        int r = idx / K, c = idx % K;
        int node = base + r;
        float v = 0.f;
        if (node < N) {
            Tin t = in[(long long)node * K + c];
            if constexpr (sizeof(Tin) == 2) v = bf2f((unsigned short)t);
            else v = (float)t;
        }
        sIn[idx] = v;
    }
    __syncthreads();
    int j = tid & 63;
    int si = tid >> 6;
#pragma unroll
    for (int u = 0; u < 4; u++) {
        int r = si * 4 + u;
        int node = base + r;
        if (node >= N) continue;
        float acc = 0.f;
#pragma unroll
        for (int k = 0; k < K; k++) acc += sIn[r * K + k] * sW[k * HID + j];
        g[(long long)node * HID + j] = f2bf(dinv[node] * acc);
    }
}

// ================= gather + combine (wave-uniform scalar indices) =================
// One wave per dst node, lane = feature. The edge loop variable is wave-uniform, so
// col[j] / row bases compile to SCALAR loads & address math (SMEM pipe); per edge the
// vector work is ONE global_load_ushort + one v_add. ILP-8 independent row loads.
__global__ __launch_bounds__(256) void gather_kernel(
    const int* __restrict__ row_ptr, const int* __restrict__ col,
    const unsigned short* __restrict__ g, const float* __restrict__ dinv,
    const float* __restrict__ bias, unsigned short* __restrict__ h, int N) {
    int wv = __builtin_amdgcn_readfirstlane(threadIdx.x >> 6);  // force wave-uniform
    int node = blockIdx.x * 4 + wv;
    int lane = threadIdx.x & 63;
    if (node >= N) return;
    int beg = row_ptr[node], end = row_ptr[node + 1];
    float sum = bf2f(g[(long long)node * HID + lane]);  // self loop
    int j = beg;
    for (; j + 8 <= end; j += 8) {
        int s0 = col[j + 0], s1 = col[j + 1], s2 = col[j + 2], s3 = col[j + 3];
        int s4 = col[j + 4], s5 = col[j + 5], s6 = col[j + 6], s7 = col[j + 7];
        float f0 = bf2f(g[(long long)s0 * HID + lane]);
        float f1 = bf2f(g[(long long)s1 * HID + lane]);
        float f2 = bf2f(g[(long long)s2 * HID + lane]);
        float f3 = bf2f(g[(long long)s3 * HID + lane]);
        float f4 = bf2f(g[(long long)s4 * HID + lane]);
        float f5 = bf2f(g[(long long)s5 * HID + lane]);
        float f6 = bf2f(g[(long long)s6 * HID + lane]);
        float f7 = bf2f(g[(long long)s7 * HID + lane]);
        sum += ((f0 + f1) + (f2 + f3)) + ((f4 + f5) + (f6 + f7));
    }
    for (; j < end; j++) {
        sum += bf2f(g[(long long)col[j] * HID + lane]);
    }
    float v = dinv[node] * sum + bias[lane];
    h[(long long)node * HID + lane] = f2bf(v > 0.f ? v : 0.f);
}

// ================= pooling: segmented reduction (batch is sorted) =================
__global__ void pool_kernel(const unsigned short* __restrict__ h, const int* __restrict__ batch,
                            float* __restrict__ sums, float* __restrict__ cnt, int N) {
    int wave = blockIdx.x * 4 + (threadIdx.x >> 6);
    int lane = threadIdx.x & 63;
    int lo = wave * 64;
    if (lo >= N) return;
    int hi = min(lo + 64, N);
    int curb = batch[lo];
    float sum = 0.f;
    int nseg = 0;
    for (int i = lo; i < hi; i++) {
        int b = batch[i];
        if (b != curb) {
            atomicAdd(&sums[curb * HID + lane], sum);
            if (lane == 0) atomicAdd(&cnt[curb], (float)nseg);
            curb = b; sum = 0.f; nseg = 0;
        }
        sum += bf2f(h[(long long)i * HID + lane]);
        nseg++;
    }
    atomicAdd(&sums[curb * HID + lane], sum);
    if (lane == 0) atomicAdd(&cnt[curb], (float)nseg);
}

// ================= final MLP head =================
__global__ void final_kernel(const float* __restrict__ sums, const float* __restrict__ cnt,
                             const float* __restrict__ Wf1, const float* __restrict__ bf1,
                             const float* __restrict__ Wf2, const float* __restrict__ bf2,
                             float* __restrict__ out) {
    __shared__ float sW1[HID * 32];
    __shared__ float sW2[32];
    int tid = threadIdx.x;
    for (int idx = tid; idx < HID * 32; idx += 128) sW1[idx] = Wf1[idx];
    if (tid < 32) sW2[tid] = Wf2[tid];
    __syncthreads();
    int b = tid;
    float pooled[HID];
    float c = fmaxf(cnt[b], 1.0f);
#pragma unroll
    for (int j = 0; j < HID; j++) pooled[j] = sums[b * HID + j] / c;
    float o = bf2[0];
#pragma unroll 4
    for (int hd = 0; hd < 32; hd++) {
        float z = bf1[hd];
#pragma unroll
        for (int j = 0; j < HID; j++) z += pooled[j] * sW1[j * 32 + hd];
        z = fmaxf(z, 0.f);
        o += z * sW2[hd];
    }
    out[b] = o;
}

extern "C" void kernel_launch(void* const* d_in, const int* in_sizes, int n_in,
                              void* d_out, int out_size, void* d_ws, size_t ws_size,
                              hipStream_t stream) {
    const float* x     = (const float*)d_in[0];
    const int*   ei    = (const int*)d_in[1];
    const int*   batch = (const int*)d_in[3];
    const float* W1  = (const float*)d_in[4];
    const float* b1  = (const float*)d_in[5];
    const float* W2  = (const float*)d_in[6];
    const float* b2  = (const float*)d_in[7];
    const float* W3  = (const float*)d_in[8];
    const float* b3  = (const float*)d_in[9];
    const float* Wf1 = (const float*)d_in[10];
    const float* bf1 = (const float*)d_in[11];
    const float* Wf2 = (const float*)d_in[12];
    const float* bf2 = (const float*)d_in[13];
    float* out = (float*)d_out;

    const int N  = in_sizes[0] / 16;   // 100000
    const int E  = in_sizes[1] / 2;    // 3200000
    const int NB = (N + 63) / 64;      // 1563 buckets
    const size_t EBUF_CAP = (size_t)E + (size_t)NBLK * NB * 15;

    // workspace layout (~62 MB)
    char* ws = (char*)d_ws;
    size_t o = 0;
    float*          dinv    = (float*)(ws + o);          o += ((size_t)N * 4 + 4095) / 4096 * 4096;
    int*            row_ptr = (int*)(ws + o);            o += ((size_t)(N + 1) * 4 + 4095) / 4096 * 4096;
    int*            pptr    = (int*)(ws + o);            o += ((size_t)(NB + 1) * 4 + 4095) / 4096 * 4096;
    int*            cptr    = (int*)(ws + o);            o += ((size_t)(NB + 1) * 4 + 4095) / 4096 * 4096;
    int*            bhist   = (int*)(ws + o);            o += ((size_t)(2 * NB) * 4 + 4095) / 4096 * 4096;
    int*            bhist_pad = bhist + NB;
    int*            gcur    = (int*)(ws + o);            o += ((size_t)NB * 4 + 4095) / 4096 * 4096;
    int*            H       = (int*)(ws + o);            o += ((size_t)NBLK * NB * 4 + 4095) / 4096 * 4096;
    unsigned*       ebuf    = (unsigned*)(ws + o);       o += EBUF_CAP * 4;
    int*            col     = (int*)(ws + o);            o += (size_t)E * 4;
    unsigned short* A       = (unsigned short*)(ws + o); o += (size_t)N * HID * 2;
    unsigned short* B       = (unsigned short*)(ws + o); o += (size_t)N * HID * 2;
    float*          sums    = (float*)(ws + o);          o += 128 * HID * 4;
    float*          cnt     = (float*)(ws + o);          o += 128 * 4;
    (void)ws_size;

    const int T = 256;
    const int Cchunk = (E + NBLK - 1) / NBLK;
    const int gGm = (N + 15) / 16;
    const int gGa = (N + 3) / 4;
    const int gPool = ((N + 63) / 64 + 3) / 4;

    // ---- CSR build: aligned radix partition, then per-bucket counting sort ----
    hipMemsetAsync(bhist, 0, (size_t)(2 * NB) * 4, stream);
    radix_hist_kernel<<<NBLK, FILL_T, 0, stream>>>(ei, H, bhist, bhist_pad, E, NB, Cchunk);
    scan_kernel<<<1, T, 0, stream>>>(bhist, bhist_pad, pptr, cptr, gcur, NB);
    radix_fill_kernel<<<NBLK, FILL_T, 0, stream>>>(ei, H, gcur, ebuf, E, NB, Cchunk);
    node_csr_kernel<<<NB, T, 0, stream>>>(pptr, cptr, ebuf, row_ptr, col, dinv, N, NB);

    // ---- layer 1: x(f32, K=16) -> A -> gather -> B ----
    gemm_g_kernel<float, 16><<<gGm, T, 0, stream>>>(x, W1, dinv, A, N);
    gather_kernel<<<gGa, T, 0, stream>>>(row_ptr, col, A, dinv, b1, B, N);

    // ---- layer 2: B -> B (in-place gemm) -> gather -> A ----
    gemm_g_kernel<unsigned short, 64><<<gGm, T, 0, stream>>>(B, W2, dinv, B, N);
    gather_kernel<<<gGa, T, 0, stream>>>(row_ptr, col, B, dinv, b2, A, N);

    // ---- layer 3: A -> A -> gather -> B ----
    gemm_g_kernel<unsigned short, 64><<<gGm, T, 0, stream>>>(A, W3, dinv, A, N);
    gather_kernel<<<gGa, T, 0, stream>>>(row_ptr, col, A, dinv, b3, B, N);

    // ---- pool + head ----
    hipMemsetAsync(sums, 0, (128 * HID + 128) * 4, stream);
    pool_kernel<<<gPool, T, 0, stream>>>(B, batch, sums, cnt, N);
    final_kernel<<<1, 128, 0, stream>>>(sums, cnt, Wf1, bf1, Wf2, bf2, out);
}